// Round 1
// 427.401 us; speedup vs baseline: 1.0917x; 1.0917x over previous
//
#include <hip/hip_runtime.h>
#include <hip/hip_bf16.h>
#include <stdint.h>

#define IN_F  4096
#define OUT_F 4096
#define BSZ   4
#define SEQ   2048
#define MDIM  (BSZ * SEQ)   // 8192

// ---------------- address-space helpers for global_load_lds ----------------
typedef __attribute__((address_space(1))) uint8_t ga_u8_t;
typedef __attribute__((address_space(3))) uint8_t ls_u8_t;

__device__ __forceinline__ void gload16_lds(const void* g, void* l) {
    // 16B-wide direct global->LDS DMA (global_load_lds_dwordx4)
    __builtin_amdgcn_global_load_lds((ga_u8_t*)g, (ls_u8_t*)l, 16, 0, 0);
}

// round-to-nearest-even fp32 -> bf16, returned as fp32 value
__device__ __forceinline__ float bf16_rne(float f) {
    unsigned u = __float_as_uint(f);
    u = (u + 0x7fffu + ((u >> 16) & 1u)) & 0xffff0000u;
    return __uint_as_float(u);
}

// ---------------- pass 1: global amax of |x| ----------------
__global__ void amax_kernel(const float* __restrict__ x, int n4,
                            unsigned int* __restrict__ amax_u) {
    const float4* x4 = (const float4*)x;
    int idx = blockIdx.x * blockDim.x + threadIdx.x;
    int stride = gridDim.x * blockDim.x;
    float m = 0.0f;
    for (int i = idx; i < n4; i += stride) {
        float4 v = x4[i];
        m = fmaxf(m, fmaxf(fmaxf(fabsf(v.x), fabsf(v.y)),
                           fmaxf(fabsf(v.z), fabsf(v.w))));
    }
    for (int off = 32; off > 0; off >>= 1)
        m = fmaxf(m, __shfl_down(m, off, 64));
    __shared__ float sm[4];
    int lane = threadIdx.x & 63, wave = threadIdx.x >> 6;
    if (lane == 0) sm[wave] = m;
    __syncthreads();
    if (threadIdx.x == 0) {
        m = fmaxf(fmaxf(sm[0], sm[1]), fmaxf(sm[2], sm[3]));
        atomicMax(amax_u, __float_as_uint(m));  // valid: all values >= 0
    }
}

// ---------------- pass 2: quantize x -> int8 AND repack w -> int8 ----------
__global__ void prep_kernel(const float* __restrict__ x,
                            const int* __restrict__ w,
                            signed char* __restrict__ x8,
                            signed char* __restrict__ w8,
                            const unsigned int* __restrict__ amax_u,
                            int nx4, int nw4) {
    int idx = blockIdx.x * blockDim.x + threadIdx.x;
    if (idx < nx4) {
        float amax = __uint_as_float(*amax_u);
        float xs = (amax == 0.0f) ? 1.0f : (amax / 127.0f);  // ref: amax/127
        float4 v = ((const float4*)x)[idx];
        char4 q;
        q.x = (signed char)fminf(fmaxf(rintf(v.x / xs), -127.0f), 127.0f);
        q.y = (signed char)fminf(fmaxf(rintf(v.y / xs), -127.0f), 127.0f);
        q.z = (signed char)fminf(fmaxf(rintf(v.z / xs), -127.0f), 127.0f);
        q.w = (signed char)fminf(fmaxf(rintf(v.w / xs), -127.0f), 127.0f);
        ((char4*)x8)[idx] = q;
    } else {
        int widx = idx - nx4;
        if (widx < nw4) {
            int4 v = ((const int4*)w)[widx];
            char4 q;
            q.x = (signed char)v.x; q.y = (signed char)v.y;
            q.z = (signed char)v.z; q.w = (signed char)v.w;
            ((char4*)w8)[widx] = q;
        }
    }
}

// ---------------- pass 3: int8 GEMM, 256x256 tile, 8-phase schedule -------
// R3: T3+T4 port of the 256^2 8-phase template (counted vmcnt, never 0 in
// the main loop) to int8. 512 threads = 8 waves (2M x 4N), per-wave output
// 128x64, BK=64, mfma_i32_16x16x64_i8 (32 MFMA/wave/K-tile, 4 phases of 8).
// Triple-buffered LDS (3 x 32KB = 96KB): staging runs 2 K-tiles ahead, so
// the one wait per tile is vmcnt(4) (drains tile t+1's 4 units, leaves
// t+2's 4 in flight). XOR granule swizzle (conflict-free, verified R1) kept:
// linear LDS dst + pre-swizzled global src + swizzled ds_read (rule #21).
using i32x4 = __attribute__((ext_vector_type(4))) int;

#define FENCE() asm volatile("" ::: "memory")
#define BAR()   do { FENCE(); __builtin_amdgcn_s_barrier(); FENCE(); } while (0)
#define WAITV4() asm volatile("s_waitcnt vmcnt(4)" ::: "memory")
#define WAITV0() asm volatile("s_waitcnt vmcnt(0)" ::: "memory")
#define WAITL0() asm volatile("s_waitcnt lgkmcnt(0)" ::: "memory")

#define MFMA8(P)                                                             \
    _Pragma("unroll")                                                        \
    for (int j = 0; j < 4; ++j) {                                            \
        acc[2*(P)][j]   = __builtin_amdgcn_mfma_i32_16x16x64_i8(             \
            aX, bF[j], acc[2*(P)][j], 0, 0, 0);                              \
        acc[2*(P)+1][j] = __builtin_amdgcn_mfma_i32_16x16x64_i8(             \
            aY, bF[j], acc[2*(P)+1][j], 0, 0, 0);                            \
    }

#define PHASE_TAIL(P)                                                        \
    BAR();                                                                   \
    WAITL0();                                                                \
    __builtin_amdgcn_sched_barrier(0);                                       \
    __builtin_amdgcn_s_setprio(1);                                           \
    MFMA8(P);                                                                \
    __builtin_amdgcn_s_setprio(0);                                           \
    BAR();

// One K-tile: 4 phases, each {ds_read frags; issue 1 stage unit of tile T+2;
// barrier; lgkmcnt(0); 8 MFMA; barrier}. TW3 = the per-tile vmcnt wait,
// placed after the 4th stage issue of phase 3.
#define TILE(T, DOSTAGE, TW3)                                                \
    {                                                                        \
        const signed char* base = smem + ((T) % 3) * 32768;                  \
        signed char* sbase = smem + (((T) + 2) % 3) * 32768;                 \
        const int kst = ((T) + 2) * 64;                                      \
        /* phase 0: all 4 B frags + A pair 0 */                              \
        bF[0] = *(const i32x4*)(base + boff[0]);                             \
        bF[1] = *(const i32x4*)(base + boff[1]);                             \
        bF[2] = *(const i32x4*)(base + boff[2]);                             \
        bF[3] = *(const i32x4*)(base + boff[3]);                             \
        aX = *(const i32x4*)(base + aoff[0]);                                \
        aY = *(const i32x4*)(base + aoff[1]);                                \
        if (DOSTAGE) gload16_lds(gA0 + kst, sbase + dA0);                    \
        PHASE_TAIL(0)                                                        \
        /* phase 1 */                                                        \
        aX = *(const i32x4*)(base + aoff[2]);                                \
        aY = *(const i32x4*)(base + aoff[3]);                                \
        if (DOSTAGE) gload16_lds(gA1 + kst, sbase + dA1);                    \
        PHASE_TAIL(1)                                                        \
        /* phase 2 */                                                        \
        aX = *(const i32x4*)(base + aoff[4]);                                \
        aY = *(const i32x4*)(base + aoff[5]);                                \
        if (DOSTAGE) gload16_lds(gB0 + kst, sbase + dB0);                    \
        PHASE_TAIL(2)                                                        \
        /* phase 3 */                                                        \
        aX = *(const i32x4*)(base + aoff[6]);                                \
        aY = *(const i32x4*)(base + aoff[7]);                                \
        if (DOSTAGE) gload16_lds(gB1 + kst, sbase + dB1);                    \
        TW3;                                                                 \
        PHASE_TAIL(3)                                                        \
    }

__global__ __launch_bounds__(512, 2) void gemm_i8_kernel(
    const signed char* __restrict__ A,
    const signed char* __restrict__ B,
    const unsigned int* __restrict__ amax_u,
    const float* __restrict__ wscale_p,
    const float* __restrict__ bias,
    float* __restrict__ out) {
    __shared__ signed char smem[3 * 32768];  // 96 KB: 3 K-tile buffers

    const int tid = threadIdx.x;      // 0..511
    const int lane = tid & 63;
    const int wave = tid >> 6;        // 0..7
    const int wm = wave >> 2;         // 0..1
    const int wn = wave & 3;          // 0..3

    // Bijective XCD swizzle: 512 blocks, 8 XCDs, chunk = 64 = 4 mt x 16 nt.
    // A-panel per XCD chunk = 4*256 rows * 4K = 4 MB -> fits per-XCD L2.
    const int bid = blockIdx.x;
    const int wg = (bid & 7) * 64 + (bid >> 3);
    const int mt = wg >> 4;           // 0..31
    const int nt = wg & 15;           // 0..15
    const int tileM = mt * 256;
    const int tileN = nt * 256;

    // Staging: 4 units per K-tile, each 8KB = 512 threads x 16B.
    // LDS dst linear (g*16); swizzle applied on the GLOBAL source column:
    // LDS(row, c) holds G(row, c ^ ((row>>1)&3)).
    const int g = tid;
    const int srow = g >> 2;                              // 0..127
    const int scol = ((g & 3) ^ ((srow >> 1) & 3)) * 16;  // pre-swizzled
    const signed char* gA0 = A + (size_t)(tileM +       srow) * IN_F + scol;
    const signed char* gA1 = A + (size_t)(tileM + 128 + srow) * IN_F + scol;
    const signed char* gB0 = B + (size_t)(tileN +       srow) * IN_F + scol;
    const signed char* gB1 = B + (size_t)(tileN + 128 + srow) * IN_F + scol;
    const int dA0 = g * 16;
    const int dA1 = 8192  + g * 16;
    const int dB0 = 16384 + g * 16;
    const int dB1 = 24576 + g * 16;

    // Fragment LDS offsets (within one buffer). A frag: m = lane&15,
    // k-chunk = lane>>4; read col = kc ^ ((row>>1)&3) undoes the swizzle.
    // Bank math: granule# mod 8 = 4*(r&1) + (kc ^ ((r>>1)&3)) -> 2 lanes
    // per bank-quad = conflict-free (SQ_LDS_BANK_CONFLICT was 0 in R1).
    int aoff[8], boff[4];
    const int kc = lane >> 4;
#pragma unroll
    for (int i = 0; i < 8; ++i) {
        int r = wm * 128 + i * 16 + (lane & 15);
        aoff[i] = r * 64 + ((kc ^ ((r >> 1) & 3)) * 16);
    }
#pragma unroll
    for (int j = 0; j < 4; ++j) {
        int r = wn * 64 + j * 16 + (lane & 15);
        boff[j] = 16384 + r * 64 + ((kc ^ ((r >> 1) & 3)) * 16);
    }

    i32x4 acc[8][4] = {};
    i32x4 bF[4], aX, aY;

    // Prologue: stage tile 0 -> buf0, tile 1 -> buf1; wait tile 0 only.
    gload16_lds(gA0,      smem + dA0);
    gload16_lds(gA1,      smem + dA1);
    gload16_lds(gB0,      smem + dB0);
    gload16_lds(gB1,      smem + dB1);
    gload16_lds(gA0 + 64, smem + 32768 + dA0);
    gload16_lds(gA1 + 64, smem + 32768 + dA1);
    gload16_lds(gB0 + 64, smem + 32768 + dB0);
    gload16_lds(gB1 + 64, smem + 32768 + dB1);
    WAITV4();   // tile 0's 4 units done; tile 1's 4 still in flight
    BAR();

    // Main loop: 64 K-tiles. Tiles 0..61 stage tile t+2 (counted vmcnt(4));
    // tile 62 drains the last staged tile (vmcnt(0), epilogue only);
    // tile 63 computes with no staging and no wait.
    for (int kt = 0; kt < 62; ++kt) {
        TILE(kt, true, WAITV4());
    }
    TILE(62, false, WAITV0());
    TILE(63, false, (void)0);

    // Epilogue: out = fp32( bf16(acc) * bf16(xs*ws) ) + bias
    float amax = __uint_as_float(*amax_u);
    float xs = (amax == 0.0f) ? 1.0f : (amax / 127.0f);
    float cs = bf16_rne(xs * wscale_p[0]);

    // C/D layout (16x16): col = lane&15, row = (lane>>4)*4 + reg
#pragma unroll
    for (int j = 0; j < 4; ++j) {
        int n = tileN + wn * 64 + j * 16 + (lane & 15);
        float bz = bias[n];
#pragma unroll
        for (int i = 0; i < 8; ++i) {
            int row0 = tileM + wm * 128 + i * 16 + (lane >> 4) * 4;
#pragma unroll
            for (int r = 0; r < 4; ++r) {
                float v = bf16_rne((float)acc[i][j][r]);
                float p = bf16_rne(v * cs);
                // nontemporal: don't let the 128MB output evict A/B in L2/LLC
                __builtin_nontemporal_store(
                    p + bz, &out[(size_t)(row0 + r) * OUT_F + n]);
            }
        }
    }
}

// ---------------- launch ----------------
extern "C" void kernel_launch(void* const* d_in, const int* in_sizes, int n_in,
                              void* d_out, int out_size, void* d_ws,
                              size_t ws_size, hipStream_t stream) {
    const float* x = (const float*)d_in[0];
    const int* w_int = (const int*)d_in[1];
    const float* w_scale = (const float*)d_in[2];
    const float* bias = (const float*)d_in[3];
    float* out = (float*)d_out;

    unsigned char* ws = (unsigned char*)d_ws;
    unsigned int* amax_u = (unsigned int*)ws;                         // 4 B
    signed char* w8 = (signed char*)(ws + 64);                        // 16 MiB
    signed char* x8 = (signed char*)(ws + 64 + (size_t)OUT_F * IN_F); // 32 MiB

    hipMemsetAsync(amax_u, 0, 4, stream);

    const int n_x4 = MDIM * IN_F / 4;   // 8,388,608 float4
    const int n_w4 = OUT_F * IN_F / 4;  // 4,194,304 int4

    amax_kernel<<<4096, 256, 0, stream>>>(x, n_x4, amax_u);
    prep_kernel<<<(n_x4 + n_w4) / 256, 256, 0, stream>>>(
        x, w_int, x8, w8, amax_u, n_x4, n_w4);

    const int nblocks = (MDIM / 256) * (OUT_F / 256);  // 512
    gemm_i8_kernel<<<nblocks, 512, 0, stream>>>(x8, w8, amax_u, w_scale, bias,
                                                out);
}

// Round 2
// 424.948 us; speedup vs baseline: 1.0980x; 1.0058x over previous
//
#include <hip/hip_runtime.h>
#include <hip/hip_bf16.h>
#include <stdint.h>

#define IN_F  4096
#define OUT_F 4096
#define BSZ   4
#define SEQ   2048
#define MDIM  (BSZ * SEQ)   // 8192

// ---------------- address-space helpers for global_load_lds ----------------
typedef __attribute__((address_space(1))) uint8_t ga_u8_t;
typedef __attribute__((address_space(3))) uint8_t ls_u8_t;

__device__ __forceinline__ void gload16_lds(const void* g, void* l) {
    // 16B-wide direct global->LDS DMA (global_load_lds_dwordx4)
    __builtin_amdgcn_global_load_lds((ga_u8_t*)g, (ls_u8_t*)l, 16, 0, 0);
}

// round-to-nearest-even fp32 -> bf16, returned as fp32 value
__device__ __forceinline__ float bf16_rne(float f) {
    unsigned u = __float_as_uint(f);
    u = (u + 0x7fffu + ((u >> 16) & 1u)) & 0xffff0000u;
    return __uint_as_float(u);
}

// ---------------- pass 1: global amax of |x| ----------------
__global__ void amax_kernel(const float* __restrict__ x, int n4,
                            unsigned int* __restrict__ amax_u) {
    const float4* x4 = (const float4*)x;
    int idx = blockIdx.x * blockDim.x + threadIdx.x;
    int stride = gridDim.x * blockDim.x;
    float m = 0.0f;
    for (int i = idx; i < n4; i += stride) {
        float4 v = x4[i];
        m = fmaxf(m, fmaxf(fmaxf(fabsf(v.x), fabsf(v.y)),
                           fmaxf(fabsf(v.z), fabsf(v.w))));
    }
    for (int off = 32; off > 0; off >>= 1)
        m = fmaxf(m, __shfl_down(m, off, 64));
    __shared__ float sm[4];
    int lane = threadIdx.x & 63, wave = threadIdx.x >> 6;
    if (lane == 0) sm[wave] = m;
    __syncthreads();
    if (threadIdx.x == 0) {
        m = fmaxf(fmaxf(sm[0], sm[1]), fmaxf(sm[2], sm[3]));
        atomicMax(amax_u, __float_as_uint(m));  // valid: all values >= 0
    }
}

// ---------------- pass 2: quantize x -> int8 AND repack w -> int8 ----------
__global__ void prep_kernel(const float* __restrict__ x,
                            const int* __restrict__ w,
                            signed char* __restrict__ x8,
                            signed char* __restrict__ w8,
                            const unsigned int* __restrict__ amax_u,
                            int nx4, int nw4) {
    int idx = blockIdx.x * blockDim.x + threadIdx.x;
    if (idx < nx4) {
        float amax = __uint_as_float(*amax_u);
        float xs = (amax == 0.0f) ? 1.0f : (amax / 127.0f);  // ref: amax/127
        float4 v = ((const float4*)x)[idx];
        char4 q;
        q.x = (signed char)fminf(fmaxf(rintf(v.x / xs), -127.0f), 127.0f);
        q.y = (signed char)fminf(fmaxf(rintf(v.y / xs), -127.0f), 127.0f);
        q.z = (signed char)fminf(fmaxf(rintf(v.z / xs), -127.0f), 127.0f);
        q.w = (signed char)fminf(fmaxf(rintf(v.w / xs), -127.0f), 127.0f);
        ((char4*)x8)[idx] = q;
    } else {
        int widx = idx - nx4;
        if (widx < nw4) {
            int4 v = ((const int4*)w)[widx];
            char4 q;
            q.x = (signed char)v.x; q.y = (signed char)v.y;
            q.z = (signed char)v.z; q.w = (signed char)v.w;
            ((char4*)w8)[widx] = q;
        }
    }
}

// ---------------- pass 3: int8 GEMM, 256x256 tile, pipelined phases -------
// R2: R1's lockstep exposed all ds_reads serially between barriers (model:
// 576+326 + 3x(192+326) ~ 2810 cy/tile = observed 703 cy/phase, MfmaUtil 39%).
// Fix: each phase prefetches the NEXT phase's fragments into an alternate
// register bank BEFORE its MFMA cluster, with counted lgkmcnt (never 0 in
// the main loop) + sched_barrier(0) (rule #18). Read schedule rebalanced to
// 2/2/4/4 per phase; per-tile vmcnt moved to phase 2 (vmcnt(3) confirms
// tile T+1's 4 staging units, leaving this tile's 3 issued units in flight)
// so phases 2/3 can prefetch next tile's B frags + first A pair. Barriers
// stay 2/phase: closing BAR after counted-lgkm MFMA guarantees all reads of
// buf(T-1) retired before any wave issues staging T+2 -> buf(T-1).
using i32x4 = __attribute__((ext_vector_type(4))) int;

#define FENCE() asm volatile("" ::: "memory")
#define BAR()   do { FENCE(); __builtin_amdgcn_s_barrier(); FENCE(); } while (0)
#define WAITV(N) asm volatile("s_waitcnt vmcnt(" #N ")" ::: "memory")
#define WAITL(N) asm volatile("s_waitcnt lgkmcnt(" #N ")" ::: "memory")
#define SB()    __builtin_amdgcn_sched_barrier(0)
#define PRIO1() __builtin_amdgcn_s_setprio(1)
#define PRIO0() __builtin_amdgcn_s_setprio(0)

#define MFMA_PH(P, X, Y, BF)                                                 \
    _Pragma("unroll")                                                        \
    for (int j = 0; j < 4; ++j) {                                            \
        acc[2*(P)][j]   = __builtin_amdgcn_mfma_i32_16x16x64_i8(             \
            X, BF[j], acc[2*(P)][j], 0, 0, 0);                               \
        acc[2*(P)+1][j] = __builtin_amdgcn_mfma_i32_16x16x64_i8(             \
            Y, BF[j], acc[2*(P)+1][j], 0, 0, 0);                             \
    }

// One tile. BFc = this tile's B bank (already loaded), BFn = next tile's
// B bank (prefetched in ph2/ph3). A banks p*/q* alternate per phase with
// fixed parity: ph0 consumes p (filled by prev tile ph3), ph3 refills p for
// the next tile. WVC2: per-tile vmcnt (phase 2). WL2/WL3: counted lgkm
// waits for phases 2/3 (differ only for the final, no-prefetch tile).
#define TILE_P(T, BFc, BFn, DOSTAGE, DOPREF, WVC2, WL2, WL3)                 \
  {                                                                          \
    const signed char* base  = smem + ((T) % 3) * 32768;                     \
    const signed char* nbase = smem + (((T) + 1) % 3) * 32768;               \
    signed char* sbase = smem + (((T) + 2) % 3) * 32768;                     \
    const int kst = ((T) + 2) * 64;                                          \
    /* ph0: consume p(a0,a1)xBFc; prefetch q <- a2,a3 */                     \
    q0 = *(const i32x4*)(base + aoff[2]);                                    \
    q1 = *(const i32x4*)(base + aoff[3]);                                    \
    if (DOSTAGE) gload16_lds(gA0 + kst, sbase + dA0);                        \
    BAR(); WAITL(2); SB(); PRIO1();                                          \
    MFMA_PH(0, p0, p1, BFc); PRIO0(); BAR();                                 \
    /* ph1: consume q; prefetch p <- a4,a5 */                                \
    p0 = *(const i32x4*)(base + aoff[4]);                                    \
    p1 = *(const i32x4*)(base + aoff[5]);                                    \
    if (DOSTAGE) gload16_lds(gA1 + kst, sbase + dA1);                        \
    BAR(); WAITL(2); SB(); PRIO1();                                          \
    MFMA_PH(1, q0, q1, BFc); PRIO0(); BAR();                                 \
    /* ph2: consume p; prefetch q <- a6,a7; vmcnt confirms buf(T+1); then    \
       (post-BAR) start next tile's B prefetch */                            \
    q0 = *(const i32x4*)(base + aoff[6]);                                    \
    q1 = *(const i32x4*)(base + aoff[7]);                                    \
    if (DOSTAGE) gload16_lds(gB0 + kst, sbase + dB0);                        \
    WVC2;                                                                    \
    BAR();                                                                   \
    if (DOPREF) {                                                            \
        BFn[0] = *(const i32x4*)(nbase + boff[0]);                           \
        BFn[1] = *(const i32x4*)(nbase + boff[1]);                           \
    }                                                                        \
    WL2; SB(); PRIO1();                                                      \
    MFMA_PH(2, p0, p1, BFc); PRIO0(); BAR();                                 \
    /* ph3: consume q; prefetch rest of next tile (BFn[2,3] + p pair) */     \
    if (DOPREF) {                                                            \
        BFn[2] = *(const i32x4*)(nbase + boff[2]);                           \
        BFn[3] = *(const i32x4*)(nbase + boff[3]);                           \
        p0 = *(const i32x4*)(nbase + aoff[0]);                               \
        p1 = *(const i32x4*)(nbase + aoff[1]);                               \
    }                                                                        \
    if (DOSTAGE) gload16_lds(gB1 + kst, sbase + dB1);                        \
    BAR(); WL3; SB(); PRIO1();                                               \
    MFMA_PH(3, q0, q1, BFc); PRIO0(); BAR();                                 \
  }

__global__ __launch_bounds__(512, 2) void gemm_i8_kernel(
    const signed char* __restrict__ A,
    const signed char* __restrict__ B,
    const unsigned int* __restrict__ amax_u,
    const float* __restrict__ wscale_p,
    const float* __restrict__ bias,
    float* __restrict__ out) {
    __shared__ signed char smem[3 * 32768];  // 96 KB: 3 K-tile buffers

    const int tid = threadIdx.x;      // 0..511
    const int lane = tid & 63;
    const int wave = tid >> 6;        // 0..7
    const int wm = wave >> 2;         // 0..1
    const int wn = wave & 3;          // 0..3

    // Bijective XCD swizzle: 512 blocks, 8 XCDs, chunk = 64 = 4 mt x 16 nt.
    const int bid = blockIdx.x;
    const int wg = (bid & 7) * 64 + (bid >> 3);
    const int mt = wg >> 4;           // 0..31
    const int nt = wg & 15;           // 0..15
    const int tileM = mt * 256;
    const int tileN = nt * 256;

    // Staging: 4 units per K-tile, each 8KB = 512 threads x 16B.
    // LDS dst linear (g*16); swizzle applied on the GLOBAL source column:
    // LDS(row, c) holds G(row, c ^ ((row>>1)&3)).
    const int g = tid;
    const int srow = g >> 2;                              // 0..127
    const int scol = ((g & 3) ^ ((srow >> 1) & 3)) * 16;  // pre-swizzled
    const signed char* gA0 = A + (size_t)(tileM +       srow) * IN_F + scol;
    const signed char* gA1 = A + (size_t)(tileM + 128 + srow) * IN_F + scol;
    const signed char* gB0 = B + (size_t)(tileN +       srow) * IN_F + scol;
    const signed char* gB1 = B + (size_t)(tileN + 128 + srow) * IN_F + scol;
    const int dA0 = g * 16;
    const int dA1 = 8192  + g * 16;
    const int dB0 = 16384 + g * 16;
    const int dB1 = 24576 + g * 16;

    // Fragment LDS offsets (within one buffer). A frag: m = lane&15,
    // k-chunk = lane>>4; read col = kc ^ ((row>>1)&3) undoes the swizzle.
    // Conflict-free (SQ_LDS_BANK_CONFLICT == 0 measured R0/R1).
    int aoff[8], boff[4];
    const int kc = lane >> 4;
#pragma unroll
    for (int i = 0; i < 8; ++i) {
        int r = wm * 128 + i * 16 + (lane & 15);
        aoff[i] = r * 64 + ((kc ^ ((r >> 1) & 3)) * 16);
    }
#pragma unroll
    for (int j = 0; j < 4; ++j) {
        int r = wn * 64 + j * 16 + (lane & 15);
        boff[j] = 16384 + r * 64 + ((kc ^ ((r >> 1) & 3)) * 16);
    }

    i32x4 acc[8][4] = {};
    i32x4 bA[4], bB[4];        // B-fragment banks (swap per tile, static)
    i32x4 p0, p1, q0, q1;      // A-fragment banks (fixed per-phase parity)

    // Prologue: stage tile 0 -> buf0, tile 1 -> buf1; wait tile 0 only.
    gload16_lds(gA0,      smem + dA0);
    gload16_lds(gA1,      smem + dA1);
    gload16_lds(gB0,      smem + dB0);
    gload16_lds(gB1,      smem + dB1);
    gload16_lds(gA0 + 64, smem + 32768 + dA0);
    gload16_lds(gA1 + 64, smem + 32768 + dA1);
    gload16_lds(gB0 + 64, smem + 32768 + dB0);
    gload16_lds(gB1 + 64, smem + 32768 + dB1);
    WAITV(4);   // tile 0's 4 units done; tile 1's 4 still in flight
    BAR();
    // Preload tile 0's B bank + first A pair (6 reads; confirmed by tile 0
    // phase 0's lgkmcnt(2)).
    bA[0] = *(const i32x4*)(smem + boff[0]);
    bA[1] = *(const i32x4*)(smem + boff[1]);
    bA[2] = *(const i32x4*)(smem + boff[2]);
    bA[3] = *(const i32x4*)(smem + boff[3]);
    p0 = *(const i32x4*)(smem + aoff[0]);
    p1 = *(const i32x4*)(smem + aoff[1]);

    // Main loop: tiles 0..61 stage tile T+2 and prefetch tile T+1.
    // Tile 62: no staging, vmcnt(0) drains tile 63's staging, prefetch 63.
    // Tile 63: no staging, no prefetch, final lgkm waits shrink.
    for (int kt = 0; kt < 62; kt += 2) {
        TILE_P(kt,     bA, bB, 1, 1, WAITV(3), WAITL(4), WAITL(6));
        TILE_P(kt + 1, bB, bA, 1, 1, WAITV(3), WAITL(4), WAITL(6));
    }
    TILE_P(62, bA, bB, 0, 1, WAITV(0), WAITL(4), WAITL(6));
    TILE_P(63, bB, bA, 0, 0, (void)0,  WAITL(2), WAITL(0));

    // Epilogue: out = fp32( bf16(acc) * bf16(xs*ws) ) + bias
    float amax = __uint_as_float(*amax_u);
    float xs = (amax == 0.0f) ? 1.0f : (amax / 127.0f);
    float cs = bf16_rne(xs * wscale_p[0]);

    // C/D layout (16x16): col = lane&15, row = (lane>>4)*4 + reg
#pragma unroll
    for (int j = 0; j < 4; ++j) {
        int n = tileN + wn * 64 + j * 16 + (lane & 15);
        float bz = bias[n];
#pragma unroll
        for (int i = 0; i < 8; ++i) {
            int row0 = tileM + wm * 128 + i * 16 + (lane >> 4) * 4;
#pragma unroll
            for (int r = 0; r < 4; ++r) {
                float v = bf16_rne((float)acc[i][j][r]);
                float p = bf16_rne(v * cs);
                // nontemporal: don't let the 128MB output evict A/B in L2/LLC
                __builtin_nontemporal_store(
                    p + bz, &out[(size_t)(row0 + r) * OUT_F + n]);
            }
        }
    }
}

// ---------------- launch ----------------
extern "C" void kernel_launch(void* const* d_in, const int* in_sizes, int n_in,
                              void* d_out, int out_size, void* d_ws,
                              size_t ws_size, hipStream_t stream) {
    const float* x = (const float*)d_in[0];
    const int* w_int = (const int*)d_in[1];
    const float* w_scale = (const float*)d_in[2];
    const float* bias = (const float*)d_in[3];
    float* out = (float*)d_out;

    unsigned char* ws = (unsigned char*)d_ws;
    unsigned int* amax_u = (unsigned int*)ws;                         // 4 B
    signed char* w8 = (signed char*)(ws + 64);                        // 16 MiB
    signed char* x8 = (signed char*)(ws + 64 + (size_t)OUT_F * IN_F); // 32 MiB

    hipMemsetAsync(amax_u, 0, 4, stream);

    const int n_x4 = MDIM * IN_F / 4;   // 8,388,608 float4
    const int n_w4 = OUT_F * IN_F / 4;  // 4,194,304 int4

    amax_kernel<<<4096, 256, 0, stream>>>(x, n_x4, amax_u);
    prep_kernel<<<(n_x4 + n_w4) / 256, 256, 0, stream>>>(
        x, w_int, x8, w8, amax_u, n_x4, n_w4);

    const int nblocks = (MDIM / 256) * (OUT_F / 256);  // 512
    gemm_i8_kernel<<<nblocks, 512, 0, stream>>>(x8, w8, amax_u, w_scale, bias,
                                                out);
}